// Round 4
// baseline (158.155 us; speedup 1.0000x reference)
//
#include <hip/hip_runtime.h>
#include <hip/hip_bf16.h>

#define TPB 256

typedef __attribute__((ext_vector_type(8))) short bf16x8;
typedef __attribute__((ext_vector_type(4))) float f32x4;

__device__ inline unsigned short f2bf(float f) {
    unsigned u = __float_as_uint(f);
    unsigned r = u + 0x7fffu + ((u >> 16) & 1u);
    return (unsigned short)(r >> 16);
}
__device__ inline float bf2f(unsigned short s) {
    return __uint_as_float(((unsigned)s) << 16);
}

// ---- pure streaming convert: h -> (h_hi bf16 ws, h_lo bf16 in d_out), W -> bf16.
// Also zeroes deg (kills the memset dispatch). No atomics anywhere.
__global__ void k_prep(const float* __restrict__ h, const float* __restrict__ W,
                       unsigned short* __restrict__ h_hi, char* __restrict__ outb,
                       unsigned short* __restrict__ Wb, int* __restrict__ deg, int N) {
    int t = blockIdx.x * TPB + threadIdx.x;
    int nh4 = N * 32;                       // N*128/4 float4 groups
    if (t < N) deg[t] = 0;
    if (t < nh4) {
        float4 v = ((const float4*)h)[t];
        ushort4 hi, lo;
        hi.x = f2bf(v.x); lo.x = f2bf(v.x - bf2f(hi.x));
        hi.y = f2bf(v.y); lo.y = f2bf(v.y - bf2f(hi.y));
        hi.z = f2bf(v.z); lo.z = f2bf(v.z - bf2f(hi.z));
        hi.w = f2bf(v.w); lo.w = f2bf(v.w - bf2f(hi.w));
        ((ushort4*)h_hi)[t] = hi;
        int row = t >> 5;
        int k   = (t & 31) << 2;
        *(ushort4*)(outb + (size_t)row * 512 + 256 + (size_t)k * 2) = lo;
    } else if (t - nh4 < 8192) {            // 128*256/4 W groups
        int w4 = t - nh4;
        float4 v = ((const float4*)W)[w4];
        ushort4 hi;
        hi.x = f2bf(v.x); hi.y = f2bf(v.y);
        hi.z = f2bf(v.z); hi.w = f2bf(v.w);
        ((ushort4*)Wb)[w4] = hi;
    }
}

// ---- XCD-sliced degree histogram: slice=blockIdx&7 -> one XCD; atomics only
// for dst in this slice's node range -> deg lines stay in that XCD's L2.
// Fire-and-forget (no return value), so no wave stall.
__global__ void k_deg(const int* __restrict__ dst, int* __restrict__ deg,
                      int N, int E, int nchunk) {
    int slice = blockIdx.x & 7;
    int chunk = blockIdx.x >> 3;
    int lo = (int)((long long)N * slice >> 3);
    int hi = (int)((long long)N * (slice + 1) >> 3);
    for (int e = chunk * TPB + threadIdx.x; e < E; e += nchunk * TPB) {
        int d = dst[e];
        if (d >= lo && d < hi) atomicAdd(&deg[d], 1);
    }
}

// ---- per-block partial sums of deg ----
__global__ void k_bsum(const int* __restrict__ deg, int* __restrict__ bsum, int N) {
    __shared__ int sdata[4];
    int i = blockIdx.x * TPB + threadIdx.x;
    int v = (i < N) ? deg[i] : 0;
    for (int o = 32; o; o >>= 1) v += __shfl_xor(v, o);
    int lane = threadIdx.x & 63, w = threadIdx.x >> 6;
    if (lane == 0) sdata[w] = v;
    __syncthreads();
    if (threadIdx.x == 0) bsum[blockIdx.x] = sdata[0] + sdata[1] + sdata[2] + sdata[3];
}

// ---- fused scan: every block redundantly scans bsum (NB<=TPB) in LDS, then
// does its local exclusive scan of deg -> offs + cursor. One dispatch.
__global__ void k_offs(const int* __restrict__ deg, const int* __restrict__ bsum,
                       int NB, int* __restrict__ offs, int* __restrict__ cursor,
                       int N, int E) {
    __shared__ int wsum[4];
    __shared__ int sb[TPB];
    int t = threadIdx.x;
    int lane = t & 63, w = t >> 6;
    // exclusive scan of bsum[0..NB)
    int v = (t < NB) ? bsum[t] : 0;
    int x = v;
    for (int o = 1; o < 64; o <<= 1) { int y = __shfl_up(x, o); if (lane >= o) x += y; }
    if (lane == 63) wsum[w] = x;
    __syncthreads();
    int add = 0;
    for (int k = 0; k < w; ++k) add += wsum[k];
    sb[t] = add + x - v;
    __syncthreads();
    int base = sb[blockIdx.x];
    // local exclusive scan of this block's deg chunk (safe to overwrite wsum:
    // all adds above completed before the barrier)
    int i = blockIdx.x * TPB + t;
    int dv = (i < N) ? deg[i] : 0;
    int y2 = dv;
    for (int o = 1; o < 64; o <<= 1) { int z = __shfl_up(y2, o); if (lane >= o) y2 += z; }
    if (lane == 63) wsum[w] = y2;
    __syncthreads();
    int add2 = 0;
    for (int k = 0; k < w; ++k) add2 += wsum[k];
    int ex = base + add2 + y2 - dv;
    if (i < N) { offs[i] = ex; cursor[i] = ex; }
    if (i == N - 1) offs[N] = E;
}

// ---- XCD-sliced scatter with slice-local cursor atomics (rank array gone):
// cursor and esrc lines each touched by exactly one XCD.
__global__ void k_scatter(const int* __restrict__ src, const int* __restrict__ dst,
                          int* __restrict__ cursor, unsigned short* __restrict__ esrc,
                          int N, int E, int nchunk) {
    int slice = blockIdx.x & 7;
    int chunk = blockIdx.x >> 3;
    int lo = (int)((long long)N * slice >> 3);
    int hi = (int)((long long)N * (slice + 1) >> 3);
    for (int e = chunk * TPB + threadIdx.x; e < E; e += nchunk * TPB) {
        int d = dst[e];
        if (d >= lo && d < hi) {
            int pos = atomicAdd(&cursor[d], 1);
            esrc[pos] = (unsigned short)src[e];
        }
    }
}

// ---- mean aggregate over bf16 h_hi; write c (bf16) interleaved into d_out ----
__global__ void k_agg(const unsigned short* __restrict__ h_hi, const int* __restrict__ offs,
                      const unsigned short* __restrict__ esrc, char* __restrict__ outb, int N) {
    int wid = (blockIdx.x * TPB + threadIdx.x) >> 6;
    int lane = threadIdx.x & 63;
    if (wid >= N) return;
    int beg = offs[wid], end = offs[wid + 1];
    const unsigned* h2 = (const unsigned*)h_hi;
    float ax0 = 0.f, ay0 = 0.f, ax1 = 0.f, ay1 = 0.f;
    int e = beg;
    for (; e + 3 < end; e += 4) {
        int s0 = esrc[e], s1 = esrc[e + 1], s2 = esrc[e + 2], s3 = esrc[e + 3];
        unsigned u0 = h2[(size_t)s0 * 64 + lane];
        unsigned u1 = h2[(size_t)s1 * 64 + lane];
        unsigned u2 = h2[(size_t)s2 * 64 + lane];
        unsigned u3 = h2[(size_t)s3 * 64 + lane];
        ax0 += __uint_as_float(u0 << 16) + __uint_as_float(u1 << 16);
        ay0 += __uint_as_float(u0 & 0xffff0000u) + __uint_as_float(u1 & 0xffff0000u);
        ax1 += __uint_as_float(u2 << 16) + __uint_as_float(u3 << 16);
        ay1 += __uint_as_float(u2 & 0xffff0000u) + __uint_as_float(u3 & 0xffff0000u);
    }
    for (; e < end; ++e) {
        unsigned u0 = h2[(size_t)esrc[e] * 64 + lane];
        ax0 += __uint_as_float(u0 << 16);
        ay0 += __uint_as_float(u0 & 0xffff0000u);
    }
    float ax = ax0 + ax1, ay = ay0 + ay1;
    float inv = 1.0f / fmaxf((float)(end - beg), 1.0f);
    unsigned pk = ((unsigned)f2bf(ay * inv) << 16) | (unsigned)f2bf(ax * inv);
    *(unsigned*)(outb + (size_t)wid * 512 + (size_t)lane * 4) = pk;
}

// ---- MFMA NodeApply: per wave 32 rows x 128 cols (391 blocks for CU coverage) ----
__launch_bounds__(TPB)
__global__ void k_apply(const unsigned short* __restrict__ h_hi,
                        const char* __restrict__ cl,        // d_out bytes: c + h_lo interleaved
                        const unsigned short* __restrict__ Wb,
                        const float* __restrict__ h,
                        const float* __restrict__ bia,
                        const float* __restrict__ snorm,
                        float* __restrict__ out, int N) {
    int lane = threadIdx.x & 63;
    int l15 = lane & 15, l4 = lane >> 4;
    int wave = threadIdx.x >> 6;
    int r0 = blockIdx.x * 128 + wave * 32;

    f32x4 acc[2][8] = {};

    #pragma unroll 2
    for (int kc = 0; kc < 8; ++kc) {
        bf16x8 Bf[8];
        #pragma unroll
        for (int n = 0; n < 8; ++n) {
            Bf[n] = *(const bf16x8*)((const char*)Wb +
                     ((size_t)(n * 16 + l15) * 512 + (size_t)kc * 64 + (size_t)l4 * 16));
        }
        #pragma unroll
        for (int rf = 0; rf < 2; ++rf) {
            int row = r0 + rf * 16 + l15;
            if (row > N - 1) row = N - 1;
            if (kc < 4) {
                bf16x8 ah = *(const bf16x8*)((const char*)h_hi +
                             ((size_t)row * 256 + (size_t)kc * 64 + (size_t)l4 * 16));
                bf16x8 al = *(const bf16x8*)(cl +
                             ((size_t)row * 512 + 256 + (size_t)kc * 64 + (size_t)l4 * 16));
                #pragma unroll
                for (int n = 0; n < 8; ++n) {
                    acc[rf][n] = __builtin_amdgcn_mfma_f32_16x16x32_bf16(ah, Bf[n], acc[rf][n], 0, 0, 0);
                    acc[rf][n] = __builtin_amdgcn_mfma_f32_16x16x32_bf16(al, Bf[n], acc[rf][n], 0, 0, 0);
                }
            } else {
                bf16x8 ac = *(const bf16x8*)(cl +
                             ((size_t)row * 512 + (size_t)(kc - 4) * 64 + (size_t)l4 * 16));
                #pragma unroll
                for (int n = 0; n < 8; ++n)
                    acc[rf][n] = __builtin_amdgcn_mfma_f32_16x16x32_bf16(ac, Bf[n], acc[rf][n], 0, 0, 0);
            }
        }
    }

    float bn[8];
    #pragma unroll
    for (int n = 0; n < 8; ++n) bn[n] = bia[n * 16 + l15];

    #pragma unroll
    for (int rf = 0; rf < 2; ++rf) {
        float sq[4] = {0.f, 0.f, 0.f, 0.f};
        #pragma unroll
        for (int n = 0; n < 8; ++n) {
            #pragma unroll
            for (int g = 0; g < 4; ++g) {
                acc[rf][n][g] += bn[n];
                sq[g] += acc[rf][n][g] * acc[rf][n][g];
            }
        }
        #pragma unroll
        for (int g = 0; g < 4; ++g) {
            sq[g] += __shfl_xor(sq[g], 1);
            sq[g] += __shfl_xor(sq[g], 2);
            sq[g] += __shfl_xor(sq[g], 4);
            sq[g] += __shfl_xor(sq[g], 8);
        }
        #pragma unroll
        for (int g = 0; g < 4; ++g) {
            int row = r0 + rf * 16 + l4 * 4 + g;
            if (row < N) {
                float invn = 1.0f / fmaxf(sqrtf(sq[g]), 1e-12f);
                float sn = snorm[row];
                #pragma unroll
                for (int n = 0; n < 8; ++n) {
                    int col = n * 16 + l15;
                    float v = fmaxf(acc[rf][n][g] * invn, 0.f) * sn + h[(size_t)row * 128 + col];
                    out[(size_t)row * 128 + col] = v;
                }
            }
        }
    }
}

extern "C" void kernel_launch(void* const* d_in, const int* in_sizes, int n_in,
                              void* d_out, int out_size, void* d_ws, size_t ws_size,
                              hipStream_t stream) {
    const float* h     = (const float*)d_in[0];
    const float* snorm = (const float*)d_in[1];
    const float* W     = (const float*)d_in[2];
    const float* b     = (const float*)d_in[3];
    const int*   src   = (const int*)d_in[4];
    const int*   dst   = (const int*)d_in[5];
    int N = in_sizes[1];
    int E = in_sizes[4];
    float* out = (float*)d_out;
    char* outb = (char*)d_out;

    char* ws = (char*)d_ws;
    size_t off = 0;
    auto alloc = [&](size_t bytes) {
        void* ptr = ws + off;
        off = (off + bytes + 255) & ~(size_t)255;
        return ptr;
    };
    int NB = (N + TPB - 1) / TPB;
    int* deg    = (int*)alloc((size_t)N * 4);
    int* offs   = (int*)alloc((size_t)(N + 1) * 4);
    int* cursor = (int*)alloc((size_t)N * 4);
    int* bsum   = (int*)alloc((size_t)NB * 4);
    unsigned short* esrc = (unsigned short*)alloc((size_t)E * 2);
    unsigned short* h_hi = (unsigned short*)alloc((size_t)N * 128 * 2);
    unsigned short* Wb   = (unsigned short*)alloc((size_t)128 * 256 * 2);

    int prep_items = N * 32 + 8192;
    k_prep<<<(prep_items + TPB - 1) / TPB, TPB, 0, stream>>>(h, W, h_hi, outb, Wb, deg, N);

    int nchunk_d = 128;
    k_deg<<<8 * nchunk_d, TPB, 0, stream>>>(dst, deg, N, E, nchunk_d);

    k_bsum<<<NB, TPB, 0, stream>>>(deg, bsum, N);
    k_offs<<<NB, TPB, 0, stream>>>(deg, bsum, NB, offs, cursor, N, E);

    int nchunk_s = 128;
    k_scatter<<<8 * nchunk_s, TPB, 0, stream>>>(src, dst, cursor, esrc, N, E, nchunk_s);

    k_agg<<<((size_t)N * 64 + TPB - 1) / TPB, TPB, 0, stream>>>(h_hi, offs, esrc, outb, N);

    int nblk = (N + 127) / 128;
    k_apply<<<nblk, TPB, 0, stream>>>(h_hi, outb, Wb, h, b, snorm, out, N);
}

// Round 5
// 135.118 us; speedup vs baseline: 1.1705x; 1.1705x over previous
//
#include <hip/hip_runtime.h>
#include <hip/hip_bf16.h>

#define TPB 256

typedef __attribute__((ext_vector_type(8))) short bf16x8;
typedef __attribute__((ext_vector_type(4))) float f32x4;

__device__ inline unsigned short f2bf(float f) {
    unsigned u = __float_as_uint(f);
    unsigned r = u + 0x7fffu + ((u >> 16) & 1u);
    return (unsigned short)(r >> 16);
}
__device__ inline float bf2f(unsigned short s) {
    return __uint_as_float(((unsigned)s) << 16);
}

// ---- fused: h -> (h_hi bf16 ws, h_lo bf16 in d_out), W -> bf16, edge deg+rank.
// Single atomic pass (4 edges/thread for RMW ILP), hidden under the streaming
// converts. deg must be zeroed (memsetAsync) before this kernel.
__global__ void k_prep(const float* __restrict__ h, const float* __restrict__ W,
                       const int* __restrict__ dst,
                       unsigned short* __restrict__ h_hi, char* __restrict__ outb,
                       unsigned short* __restrict__ Wb,
                       int* __restrict__ deg, unsigned short* __restrict__ rank,
                       int N, int E) {
    int t = blockIdx.x * TPB + threadIdx.x;
    int nh4 = N * 32;                       // N*128/4 float4 groups
    if (t < nh4) {
        float4 v = ((const float4*)h)[t];
        ushort4 hi, lo;
        hi.x = f2bf(v.x); lo.x = f2bf(v.x - bf2f(hi.x));
        hi.y = f2bf(v.y); lo.y = f2bf(v.y - bf2f(hi.y));
        hi.z = f2bf(v.z); lo.z = f2bf(v.z - bf2f(hi.z));
        hi.w = f2bf(v.w); lo.w = f2bf(v.w - bf2f(hi.w));
        ((ushort4*)h_hi)[t] = hi;
        int row = t >> 5;
        int k   = (t & 31) << 2;
        *(ushort4*)(outb + (size_t)row * 512 + 256 + (size_t)k * 2) = lo;
    } else if (t - nh4 < 8192) {            // 128*256/4 W groups
        int w4 = t - nh4;
        float4 v = ((const float4*)W)[w4];
        ushort4 hi;
        hi.x = f2bf(v.x); hi.y = f2bf(v.y);
        hi.z = f2bf(v.z); hi.w = f2bf(v.w);
        ((ushort4*)Wb)[w4] = hi;
    }
    int EQ = (E + 3) >> 2;
    if (t < EQ) {
        int e0 = t, e1 = t + EQ, e2 = t + 2 * EQ, e3 = t + 3 * EQ;
        int d0 = dst[e0];
        int d1 = (e1 < E) ? dst[e1] : 0;
        int d2 = (e2 < E) ? dst[e2] : 0;
        int d3 = (e3 < E) ? dst[e3] : 0;
        int r0 = atomicAdd(&deg[d0], 1);
        int r1 = (e1 < E) ? atomicAdd(&deg[d1], 1) : 0;
        int r2 = (e2 < E) ? atomicAdd(&deg[d2], 1) : 0;
        int r3 = (e3 < E) ? atomicAdd(&deg[d3], 1) : 0;
        rank[e0] = (unsigned short)r0;
        if (e1 < E) rank[e1] = (unsigned short)r1;
        if (e2 < E) rank[e2] = (unsigned short)r2;
        if (e3 < E) rank[e3] = (unsigned short)r3;
    }
}

// ---- per-block partial sums of deg ----
__global__ void k_bsum(const int* __restrict__ deg, int* __restrict__ bsum, int N) {
    __shared__ int sdata[4];
    int i = blockIdx.x * TPB + threadIdx.x;
    int v = (i < N) ? deg[i] : 0;
    for (int o = 32; o; o >>= 1) v += __shfl_xor(v, o);
    int lane = threadIdx.x & 63, w = threadIdx.x >> 6;
    if (lane == 0) sdata[w] = v;
    __syncthreads();
    if (threadIdx.x == 0) bsum[blockIdx.x] = sdata[0] + sdata[1] + sdata[2] + sdata[3];
}

// ---- fused scan: every block redundantly scans bsum (NB<=TPB) in LDS, then
// its local exclusive scan of deg -> offs. One dispatch.
__global__ void k_offs(const int* __restrict__ deg, const int* __restrict__ bsum,
                       int NB, int* __restrict__ offs, int N, int E) {
    __shared__ int wsum[4];
    __shared__ int sb[TPB];
    int t = threadIdx.x;
    int lane = t & 63, w = t >> 6;
    int v = (t < NB) ? bsum[t] : 0;
    int x = v;
    for (int o = 1; o < 64; o <<= 1) { int y = __shfl_up(x, o); if (lane >= o) x += y; }
    if (lane == 63) wsum[w] = x;
    __syncthreads();
    int add = 0;
    for (int k = 0; k < w; ++k) add += wsum[k];
    sb[t] = add + x - v;
    __syncthreads();
    int base = sb[blockIdx.x];
    int i = blockIdx.x * TPB + t;
    int dv = (i < N) ? deg[i] : 0;
    int y2 = dv;
    for (int o = 1; o < 64; o <<= 1) { int z = __shfl_up(y2, o); if (lane >= o) y2 += z; }
    if (lane == 63) wsum[w] = y2;
    __syncthreads();
    int add2 = 0;
    for (int k = 0; k < w; ++k) add2 += wsum[k];
    int ex = base + add2 + y2 - dv;
    if (i < N) offs[i] = ex;
    if (i == N - 1) offs[N] = E;
}

// ---- XCD-sliced, atomic-free scatter (rank precomputed): slice=blockIdx&7
// keeps each esrc line owned by one XCD's L2, written back once.
__global__ void k_scatter(const int* __restrict__ src, const int* __restrict__ dst,
                          const unsigned short* __restrict__ rank,
                          const int* __restrict__ offs,
                          unsigned short* __restrict__ esrc, int N, int E, int nchunk) {
    int slice = blockIdx.x & 7;
    int chunk = blockIdx.x >> 3;
    int lo = (int)((long long)N * slice >> 3);
    int hi = (int)((long long)N * (slice + 1) >> 3);
    for (int e = chunk * TPB + threadIdx.x; e < E; e += nchunk * TPB) {
        int d = dst[e];
        if (d >= lo && d < hi) {
            int pos = offs[d] + (int)rank[e];
            esrc[pos] = (unsigned short)src[e];
        }
    }
}

// ---- mean aggregate over bf16 h_hi; write c (bf16) interleaved into d_out ----
__global__ void k_agg(const unsigned short* __restrict__ h_hi, const int* __restrict__ offs,
                      const unsigned short* __restrict__ esrc, char* __restrict__ outb, int N) {
    int wid = (blockIdx.x * TPB + threadIdx.x) >> 6;
    int lane = threadIdx.x & 63;
    if (wid >= N) return;
    int beg = offs[wid], end = offs[wid + 1];
    const unsigned* h2 = (const unsigned*)h_hi;
    float ax0 = 0.f, ay0 = 0.f, ax1 = 0.f, ay1 = 0.f;
    int e = beg;
    for (; e + 3 < end; e += 4) {
        int s0 = esrc[e], s1 = esrc[e + 1], s2 = esrc[e + 2], s3 = esrc[e + 3];
        unsigned u0 = h2[(size_t)s0 * 64 + lane];
        unsigned u1 = h2[(size_t)s1 * 64 + lane];
        unsigned u2 = h2[(size_t)s2 * 64 + lane];
        unsigned u3 = h2[(size_t)s3 * 64 + lane];
        ax0 += __uint_as_float(u0 << 16) + __uint_as_float(u1 << 16);
        ay0 += __uint_as_float(u0 & 0xffff0000u) + __uint_as_float(u1 & 0xffff0000u);
        ax1 += __uint_as_float(u2 << 16) + __uint_as_float(u3 << 16);
        ay1 += __uint_as_float(u2 & 0xffff0000u) + __uint_as_float(u3 & 0xffff0000u);
    }
    for (; e < end; ++e) {
        unsigned u0 = h2[(size_t)esrc[e] * 64 + lane];
        ax0 += __uint_as_float(u0 << 16);
        ay0 += __uint_as_float(u0 & 0xffff0000u);
    }
    float ax = ax0 + ax1, ay = ay0 + ay1;
    float inv = 1.0f / fmaxf((float)(end - beg), 1.0f);
    unsigned pk = ((unsigned)f2bf(ay * inv) << 16) | (unsigned)f2bf(ax * inv);
    *(unsigned*)(outb + (size_t)wid * 512 + (size_t)lane * 4) = pk;
}

// ---- MFMA NodeApply, 32 rows/wave. Residual reconstructed from h_hi + h_lo
// (no f32 h read). NOTE: cl and out alias (both are d_out) -> no __restrict__
// on them; residual loads are batched before the stores for each row group,
// and wave-lockstep in-order issue makes read-before-overwrite safe.
__launch_bounds__(TPB)
__global__ void k_apply(const unsigned short* __restrict__ h_hi,
                        const char* cl,                    // d_out: c + h_lo interleaved
                        const unsigned short* __restrict__ Wb,
                        const float* __restrict__ bia,
                        const float* __restrict__ snorm,
                        float* out, int N) {
    int lane = threadIdx.x & 63;
    int l15 = lane & 15, l4 = lane >> 4;
    int wave = threadIdx.x >> 6;
    int r0 = blockIdx.x * 128 + wave * 32;

    f32x4 acc[2][8] = {};

    #pragma unroll 2
    for (int kc = 0; kc < 8; ++kc) {
        bf16x8 Bf[8];
        #pragma unroll
        for (int n = 0; n < 8; ++n) {
            Bf[n] = *(const bf16x8*)((const char*)Wb +
                     ((size_t)(n * 16 + l15) * 512 + (size_t)kc * 64 + (size_t)l4 * 16));
        }
        #pragma unroll
        for (int rf = 0; rf < 2; ++rf) {
            int row = r0 + rf * 16 + l15;
            if (row > N - 1) row = N - 1;
            if (kc < 4) {
                bf16x8 ah = *(const bf16x8*)((const char*)h_hi +
                             ((size_t)row * 256 + (size_t)kc * 64 + (size_t)l4 * 16));
                bf16x8 al = *(const bf16x8*)(cl +
                             ((size_t)row * 512 + 256 + (size_t)kc * 64 + (size_t)l4 * 16));
                #pragma unroll
                for (int n = 0; n < 8; ++n) {
                    acc[rf][n] = __builtin_amdgcn_mfma_f32_16x16x32_bf16(ah, Bf[n], acc[rf][n], 0, 0, 0);
                    acc[rf][n] = __builtin_amdgcn_mfma_f32_16x16x32_bf16(al, Bf[n], acc[rf][n], 0, 0, 0);
                }
            } else {
                bf16x8 ac = *(const bf16x8*)(cl +
                             ((size_t)row * 512 + (size_t)(kc - 4) * 64 + (size_t)l4 * 16));
                #pragma unroll
                for (int n = 0; n < 8; ++n)
                    acc[rf][n] = __builtin_amdgcn_mfma_f32_16x16x32_bf16(ac, Bf[n], acc[rf][n], 0, 0, 0);
            }
        }
    }

    float bn[8];
    #pragma unroll
    for (int n = 0; n < 8; ++n) bn[n] = bia[n * 16 + l15];

    #pragma unroll
    for (int rf = 0; rf < 2; ++rf) {
        float sq[4] = {0.f, 0.f, 0.f, 0.f};
        #pragma unroll
        for (int n = 0; n < 8; ++n) {
            #pragma unroll
            for (int g = 0; g < 4; ++g) {
                acc[rf][n][g] += bn[n];
                sq[g] += acc[rf][n][g] * acc[rf][n][g];
            }
        }
        #pragma unroll
        for (int g = 0; g < 4; ++g) {
            sq[g] += __shfl_xor(sq[g], 1);
            sq[g] += __shfl_xor(sq[g], 2);
            sq[g] += __shfl_xor(sq[g], 4);
            sq[g] += __shfl_xor(sq[g], 8);
        }
        #pragma unroll
        for (int g = 0; g < 4; ++g) {
            int row = r0 + rf * 16 + l4 * 4 + g;
            if (row < N) {
                float invn = 1.0f / fmaxf(sqrtf(sq[g]), 1e-12f);
                float sn = snorm[row];
                // batch residual loads (h_hi + h_lo) before any store to this row
                float res[8];
                #pragma unroll
                for (int n = 0; n < 8; ++n) {
                    int col = n * 16 + l15;
                    float hv = bf2f(h_hi[(size_t)row * 128 + col]);
                    float lv = bf2f(*(const unsigned short*)(cl +
                                    (size_t)row * 512 + 256 + (size_t)col * 2));
                    res[n] = hv + lv;
                }
                #pragma unroll
                for (int n = 0; n < 8; ++n) {
                    int col = n * 16 + l15;
                    out[(size_t)row * 128 + col] =
                        fmaxf(acc[rf][n][g] * invn, 0.f) * sn + res[n];
                }
            }
        }
    }
}

extern "C" void kernel_launch(void* const* d_in, const int* in_sizes, int n_in,
                              void* d_out, int out_size, void* d_ws, size_t ws_size,
                              hipStream_t stream) {
    const float* h     = (const float*)d_in[0];
    const float* snorm = (const float*)d_in[1];
    const float* W     = (const float*)d_in[2];
    const float* b     = (const float*)d_in[3];
    const int*   src   = (const int*)d_in[4];
    const int*   dst   = (const int*)d_in[5];
    int N = in_sizes[1];
    int E = in_sizes[4];
    float* out = (float*)d_out;
    char* outb = (char*)d_out;

    char* ws = (char*)d_ws;
    size_t off = 0;
    auto alloc = [&](size_t bytes) {
        void* ptr = ws + off;
        off = (off + bytes + 255) & ~(size_t)255;
        return ptr;
    };
    int NB = (N + TPB - 1) / TPB;
    int* deg    = (int*)alloc((size_t)N * 4);
    int* offs   = (int*)alloc((size_t)(N + 1) * 4);
    int* bsum   = (int*)alloc((size_t)NB * 4);
    unsigned short* rank = (unsigned short*)alloc((size_t)E * 2);
    unsigned short* esrc = (unsigned short*)alloc((size_t)E * 2);
    unsigned short* h_hi = (unsigned short*)alloc((size_t)N * 128 * 2);
    unsigned short* Wb   = (unsigned short*)alloc((size_t)128 * 256 * 2);

    hipMemsetAsync(deg, 0, (size_t)N * 4, stream);

    int prep_items = N * 32 + 8192;
    int EQ = (E + 3) >> 2;
    int prep_grid = (prep_items > EQ ? prep_items : EQ);
    k_prep<<<(prep_grid + TPB - 1) / TPB, TPB, 0, stream>>>(h, W, dst, h_hi, outb, Wb,
                                                            deg, rank, N, E);

    k_bsum<<<NB, TPB, 0, stream>>>(deg, bsum, N);
    k_offs<<<NB, TPB, 0, stream>>>(deg, bsum, NB, offs, N, E);

    int nchunk = 512;
    k_scatter<<<8 * nchunk, TPB, 0, stream>>>(src, dst, rank, offs, esrc, N, E, nchunk);

    k_agg<<<((size_t)N * 64 + TPB - 1) / TPB, TPB, 0, stream>>>(h_hi, offs, esrc, outb, N);

    int nblk = (N + 127) / 128;
    k_apply<<<nblk, TPB, 0, stream>>>(h_hi, outb, Wb, b, snorm, out, N);
}